// Round 6
// baseline (169.046 us; speedup 1.0000x reference)
//
#include <hip/hip_runtime.h>
#include <hip/hip_bf16.h>
#include <stdint.h>

typedef __bf16 bf16_t;
typedef __bf16 bf16x4 __attribute__((ext_vector_type(4)));
typedef __bf16 bf16x8 __attribute__((ext_vector_type(8)));
typedef float  f32x4  __attribute__((ext_vector_type(4)));

#define AS_GLOBAL __attribute__((address_space(1)))
#define AS_LDS    __attribute__((address_space(3)))

__device__ __forceinline__ void gload_lds16(const void* g, void* l) {
  __builtin_amdgcn_global_load_lds((const AS_GLOBAL void*)g,
                                   (AS_LDS void*)l, 16, 0, 0);
}

// ---------------- K0a: f32 -> bf16 elementwise (8 elems/thread) ----------------
__global__ void cvt_f32_bf16_kernel(const float* __restrict__ in,
                                    bf16_t* __restrict__ out) {
  const int i = blockIdx.x * blockDim.x + threadIdx.x;
  f32x4 v0 = *(const f32x4*)&in[(size_t)i * 8];
  f32x4 v1 = *(const f32x4*)&in[(size_t)i * 8 + 4];
  bf16x8 o;
  o[0] = (bf16_t)v0[0]; o[1] = (bf16_t)v0[1]; o[2] = (bf16_t)v0[2]; o[3] = (bf16_t)v0[3];
  o[4] = (bf16_t)v1[0]; o[5] = (bf16_t)v1[1]; o[6] = (bf16_t)v1[2]; o[7] = (bf16_t)v1[3];
  *(bf16x8*)&out[(size_t)i * 8] = o;
}

// ---------------- K0b: weight [512][512] f32 -> wT [512][512] bf16 (transpose) ----------------
__global__ void transpose_cvt_kernel(const float* __restrict__ in,
                                     bf16_t* __restrict__ out) {
  __shared__ float t[32][33];
  const int ti = blockIdx.x;  // din tile
  const int tj = blockIdx.y;  // dout tile
  const int c = threadIdx.x & 31;
  const int r0 = threadIdx.x >> 5;  // 0..7
  #pragma unroll
  for (int p = 0; p < 4; ++p) {
    int r = r0 + p * 8;
    t[r][c] = in[(size_t)(ti * 32 + r) * 512 + tj * 32 + c];
  }
  __syncthreads();
  #pragma unroll
  for (int p = 0; p < 4; ++p) {
    int r = r0 + p * 8;
    out[(size_t)(tj * 32 + r) * 512 + ti * 32 + c] = (bf16_t)t[c][r];
  }
}

// ---------------- K1 GEMM-BT (bf16 A, stage-ahead dbuf) — unchanged ----------------
template<int A_IS_F32, int EPI, int NI>
__global__ __launch_bounds__(512, 2) void gemm_bt32_kernel(
    const void* __restrict__ Av, const bf16_t* __restrict__ Bt,
    void* __restrict__ Cv, int nmt, int nnt, int ksteps,
    int lda, int ldb, int ldc, size_t pstride) {
  constexpr int BM = 128, BK = 32, BN = NI * 64;
  __shared__ alignas(16) bf16_t Al[2][BM * BK];
  __shared__ alignas(16) bf16_t Bl[2][BN * BK];

  const int tid  = threadIdx.x;
  const int lane = tid & 63;
  const int w    = tid >> 6;
  const int wr   = w >> 2;
  const int wc   = w & 3;

  const int nwg = gridDim.x;
  const int cpx = nwg >> 3;
  const int bid = blockIdx.x;
  const int swz = (bid & 7) * cpx + (bid >> 3);
  const int ks  = swz / (nmt * nnt);
  const int r_  = swz - ks * (nmt * nnt);
  const int nt  = r_ / nmt;
  const int mt  = r_ - nt * nmt;
  const int row0 = mt * BM;
  const int col0 = nt * BN;
  const int kst  = ks * ksteps * BK;

  f32x4 acc[4][NI];
  #pragma unroll
  for (int mi = 0; mi < 4; ++mi)
    #pragma unroll
    for (int ni = 0; ni < NI; ++ni)
      acc[mi][ni] = (f32x4){0.f, 0.f, 0.f, 0.f};

  const float*  Af = (const float*)Av;
  const bf16_t* Ab = (const bf16_t*)Av;

  const int r4   = tid >> 2;
  const int g4   = tid & 3;
  const int gsrc = g4 ^ (r4 & 3);

  f32x4 apref0, apref1;

  auto stageB = [&](int b, int k0) {
    #pragma unroll
    for (int i = 0; i < NI / 2; ++i)
      gload_lds16(&Bt[(size_t)(col0 + r4 + i * 128) * ldb + kst + k0 + gsrc * 8],
                  &Bl[b][(tid + i * 512) * 8]);
  };
  auto stageA16 = [&](int b, int k0) {
    gload_lds16(&Ab[(size_t)(row0 + r4) * lda + kst + k0 + gsrc * 8],
                &Al[b][tid * 8]);
  };
  auto loadA = [&](int k0) {
    const float* p = &Af[(size_t)(row0 + r4) * lda + kst + k0 + g4 * 8];
    apref0 = *(const f32x4*)p;
    apref1 = *(const f32x4*)(p + 4);
  };
  auto writeA = [&](int b) {
    bf16x8 v;
    v[0] = (bf16_t)apref0[0]; v[1] = (bf16_t)apref0[1];
    v[2] = (bf16_t)apref0[2]; v[3] = (bf16_t)apref0[3];
    v[4] = (bf16_t)apref1[0]; v[5] = (bf16_t)apref1[1];
    v[6] = (bf16_t)apref1[2]; v[7] = (bf16_t)apref1[3];
    *(bf16x8*)&Al[b][r4 * 32 + ((g4 ^ (r4 & 3)) << 3)] = v;
  };

  stageB(0, 0);
  if constexpr (A_IS_F32) {
    loadA(0);
    writeA(0);
    if (ksteps > 1) loadA(BK);
  } else {
    stageA16(0, 0);
  }
  __syncthreads();

  int cur = 0;
  for (int kt = 0; kt < ksteps; ++kt) {
    if (kt + 1 < ksteps) {
      stageB(cur ^ 1, (kt + 1) * BK);
      if constexpr (A_IS_F32) {
        writeA(cur ^ 1);
        if (kt + 2 < ksteps) loadA((kt + 2) * BK);
      } else {
        stageA16(cur ^ 1, (kt + 1) * BK);
      }
    }
    const int frow = lane & 15;
    const int gk = lane >> 4;
    bf16x8 a[4], b[NI];
    #pragma unroll
    for (int mi = 0; mi < 4; ++mi) {
      const int r = wr * 64 + mi * 16 + frow;
      a[mi] = *(const bf16x8*)&Al[cur][r * 32 + ((gk ^ (r & 3)) << 3)];
    }
    #pragma unroll
    for (int ni = 0; ni < NI; ++ni) {
      const int r = wc * (NI * 16) + ni * 16 + frow;
      b[ni] = *(const bf16x8*)&Bl[cur][r * 32 + ((gk ^ (r & 3)) << 3)];
    }
    #pragma unroll
    for (int mi = 0; mi < 4; ++mi)
      #pragma unroll
      for (int ni = 0; ni < NI; ++ni)
        acc[mi][ni] = __builtin_amdgcn_mfma_f32_16x16x32_bf16(a[mi], b[ni], acc[mi][ni], 0, 0, 0);
    __syncthreads();
    cur ^= 1;
  }

  const int rbase = row0 + wr * 64 + ((lane >> 4) << 2);
  const int cbase = col0 + wc * (NI * 16) + (lane & 15);
  bf16_t* C = (bf16_t*)Cv;
  #pragma unroll
  for (int mi = 0; mi < 4; ++mi)
    #pragma unroll
    for (int ni = 0; ni < NI; ++ni)
      #pragma unroll
      for (int j = 0; j < 4; ++j)
        C[(size_t)(rbase + mi * 16 + j) * ldc + cbase + ni * 16] =
            (bf16_t)acc[mi][ni][j];
  (void)pstride;
}

// ---------------- K2: adj(f32) @ fwT^T, 3-deep gload_lds pipeline ----------------
// BM=128, BN=512 (full width), BK=32, k-split 4 -> grid 256, 512 thr, 8 waves
// (2M x 4N), wave tile 64x128, acc[4][8]. A staged as f32 (3 x 16 KB), B bf16
// (3 x 32 KB) -> 144 KB LDS, 1 block/CU. Counted vmcnt(12): two stages always
// in flight across barriers (T4) -> HBM pipe never drains.
// A swizzle: rows 128 B / 8 granules, slot g^(r&7). B: rows 64 B, slot g^(r&3).
// f32->bf16 convert happens at ds_read time (VALU-cheap).
// EPI 3: bf16 partial store at Cv + ks*pstride. EPI 2: f32 atomicAdd.
template<int EPI>
__global__ __launch_bounds__(512, 2) void gemm_k2_pipe(
    const float* __restrict__ adj, const bf16_t* __restrict__ Bt,
    void* __restrict__ Cv, size_t pstride) {
  constexpr int BM = 128, BK = 32, KSTEPS = 64;
  __shared__ alignas(16) float  Afl[3][BM * BK];   // 3 x 16 KB
  __shared__ alignas(16) bf16_t Bfl[3][512 * BK];  // 3 x 32 KB

  const int tid  = threadIdx.x;
  const int lane = tid & 63;
  const int w    = tid >> 6;
  const int wr   = w >> 2;  // 0..1
  const int wc   = w & 3;   // 0..3

  // XCD chunk-swizzle, ks-major: 2 XCDs share one ks -> 2 MB B-slice L2-resident
  const int bid = blockIdx.x;
  const int swz = (bid & 7) * 32 + (bid >> 3);
  const int ks  = swz >> 6;        // 0..3
  const int mt  = swz & 63;        // 0..63
  const int row0 = mt * BM;
  const int kst  = ks * (KSTEPS * BK);

  f32x4 acc[4][8];
  #pragma unroll
  for (int mi = 0; mi < 4; ++mi)
    #pragma unroll
    for (int ni = 0; ni < 8; ++ni)
      acc[mi][ni] = (f32x4){0.f, 0.f, 0.f, 0.f};

  // staging geometry (source pre-swizzled, dest linear = uniform + lane*16B)
  const int ar = tid >> 3;                       // A rows ar, ar+64
  const int ag = (tid & 7) ^ (ar & 7);           // A source granule (4 f32)
  const int br = tid >> 2;                       // B rows br + i*128
  const int bg = (tid & 3) ^ (br & 3);           // B source granule (8 bf16)

  auto STAGE = [&](int step, int buf) {
    const int k0 = kst + step * BK;
    const float* As = &adj[(size_t)(row0 + ar) * 8192 + k0 + ag * 4];
    gload_lds16(As,               &Afl[buf][tid * 4]);
    gload_lds16(As + 64 * 8192,   &Afl[buf][(tid + 512) * 4]);
    const bf16_t* Bs = &Bt[(size_t)br * 8192 + k0 + bg * 8];
    #pragma unroll
    for (int i = 0; i < 4; ++i)
      gload_lds16(Bs + (size_t)i * 128 * 8192, &Bfl[buf][(tid + i * 512) * 8]);
  };

  // ---- prologue: 3 stages in flight, wait for stage 0 only ----
  STAGE(0, 0);
  STAGE(1, 1);
  STAGE(2, 2);
  asm volatile("s_waitcnt vmcnt(12)" ::: "memory");
  __builtin_amdgcn_sched_barrier(0);
  __builtin_amdgcn_s_barrier();

  int buf = 0;
  for (int kt = 0; kt < KSTEPS; ++kt) {
    // compute on buf
    const int frow = lane & 15;
    const int gk = lane >> 4;
    bf16x8 a[4];
    #pragma unroll
    for (int mi = 0; mi < 4; ++mi) {
      const int r = wr * 64 + mi * 16 + frow;
      const float* Ar = &Afl[buf][r * 32];
      f32x4 f0 = *(const f32x4*)(Ar + ((((gk << 1))     ^ (r & 7)) << 2));
      f32x4 f1 = *(const f32x4*)(Ar + ((((gk << 1) | 1) ^ (r & 7)) << 2));
      bf16x8 av;
      av[0] = (bf16_t)f0[0]; av[1] = (bf16_t)f0[1];
      av[2] = (bf16_t)f0[2]; av[3] = (bf16_t)f0[3];
      av[4] = (bf16_t)f1[0]; av[5] = (bf16_t)f1[1];
      av[6] = (bf16_t)f1[2]; av[7] = (bf16_t)f1[3];
      a[mi] = av;
    }
    #pragma unroll
    for (int ni = 0; ni < 8; ++ni) {
      const int r = wc * 128 + ni * 16 + frow;
      bf16x8 bv = *(const bf16x8*)&Bfl[buf][r * 32 + ((gk ^ (r & 3)) << 3)];
      #pragma unroll
      for (int mi = 0; mi < 4; ++mi)
        acc[mi][ni] = __builtin_amdgcn_mfma_f32_16x16x32_bf16(a[mi], bv, acc[mi][ni], 0, 0, 0);
    }
    __builtin_amdgcn_s_barrier();     // all waves done reading buf
    if (kt + 3 < KSTEPS) {
      STAGE(kt + 3, buf);             // refill the buffer just consumed
      asm volatile("s_waitcnt vmcnt(12)" ::: "memory");  // stage kt+1 landed
    } else if (kt + 2 < KSTEPS) {
      asm volatile("s_waitcnt vmcnt(6)" ::: "memory");
    } else if (kt + 1 < KSTEPS) {
      asm volatile("s_waitcnt vmcnt(0)" ::: "memory");
    }
    __builtin_amdgcn_sched_barrier(0);
    __builtin_amdgcn_s_barrier();     // kt+1 data visible to all waves
    buf = (buf == 2) ? 0 : buf + 1;
  }

  // epilogue: C/D layout col=lane&15, row=(lane>>4)*4+reg  [m89-verified]
  const int rbase = row0 + wr * 64 + ((lane >> 4) << 2);
  const int cbase = wc * 128 + (lane & 15);
  if constexpr (EPI == 3) {
    bf16_t* C = (bf16_t*)Cv + (size_t)ks * pstride;
    #pragma unroll
    for (int mi = 0; mi < 4; ++mi)
      #pragma unroll
      for (int ni = 0; ni < 8; ++ni)
        #pragma unroll
        for (int j = 0; j < 4; ++j)
          C[(size_t)(rbase + mi * 16 + j) * 512 + cbase + ni * 16] =
              (bf16_t)acc[mi][ni][j];
  } else {
    float* C = (float*)Cv;
    #pragma unroll
    for (int mi = 0; mi < 4; ++mi)
      #pragma unroll
      for (int ni = 0; ni < 8; ++ni)
        #pragma unroll
        for (int j = 0; j < 4; ++j)
          atomicAdd(&C[(size_t)(rbase + mi * 16 + j) * 512 + cbase + ni * 16],
                    acc[mi][ni][j]);
  }
}

// ---------------- reduce 4 bf16 partials + relu -> f32 ----------------
__global__ void reduce4_relu_kernel(const bf16_t* __restrict__ part,
                                    size_t pstride, float* __restrict__ out) {
  const size_t i8 = ((size_t)blockIdx.x * blockDim.x + threadIdx.x) * 8;
  float s[8];
  #pragma unroll
  for (int j = 0; j < 8; ++j) s[j] = 0.f;
  #pragma unroll
  for (int p = 0; p < 4; ++p) {
    bf16x8 v = *(const bf16x8*)&part[p * pstride + i8];
    #pragma unroll
    for (int j = 0; j < 8; ++j) s[j] += (float)v[j];
  }
  f32x4 r0, r1;
  r0[0] = fmaxf(s[0], 0.f); r0[1] = fmaxf(s[1], 0.f);
  r0[2] = fmaxf(s[2], 0.f); r0[3] = fmaxf(s[3], 0.f);
  r1[0] = fmaxf(s[4], 0.f); r1[1] = fmaxf(s[5], 0.f);
  r1[2] = fmaxf(s[6], 0.f); r1[3] = fmaxf(s[7], 0.f);
  *(f32x4*)&out[i8] = r0;
  *(f32x4*)&out[i8 + 4] = r1;
}

// ---------------- in-place relu (atomic fallback) ----------------
__global__ void relu_inplace_kernel(float* __restrict__ out) {
  const size_t i = ((size_t)blockIdx.x * blockDim.x + threadIdx.x) * 4;
  f32x4 a = *(const f32x4*)&out[i];
  f32x4 r;
  r[0] = fmaxf(a[0], 0.f); r[1] = fmaxf(a[1], 0.f);
  r[2] = fmaxf(a[2], 0.f); r[3] = fmaxf(a[3], 0.f);
  *(f32x4*)&out[i] = r;
}

extern "C" void kernel_launch(void* const* d_in, const int* in_sizes, int n_in,
                              void* d_out, int out_size, void* d_ws, size_t ws_size,
                              hipStream_t stream) {
  const int N = 8192, D = 512;
  const float* features = (const float*)d_in[0];  // [N][D]
  const float* adj      = (const float*)d_in[1];  // [N][N]
  const float* weight   = (const float*)d_in[2];  // [D][D]
  float* out = (float*)d_out;                     // [N][D] f32

  char* ws = (char*)d_ws;
  bf16_t* fb16 = (bf16_t*)ws;                                    // 8.39 MB
  bf16_t* wT   = (bf16_t*)(ws + (size_t)N * D * 2);              // 0.52 MB
  bf16_t* fwT  = (bf16_t*)(ws + (size_t)N * D * 2 + (size_t)D * D * 2);  // 8.39 MB
  const size_t base_bytes = (size_t)N * D * 2 * 2 + (size_t)D * D * 2;   // 17.3 MB
  bf16_t* part = (bf16_t*)(ws + base_bytes);      // 4 x 8.39 MB bf16 partials
  const size_t pstride = (size_t)N * D;
  const bool have_part = ws_size >= base_bytes + 4 * pstride * sizeof(bf16_t);

  // K0a: features f32 -> bf16
  cvt_f32_bf16_kernel<<<(N * D / 8) / 256, 256, 0, stream>>>(features, fb16);
  // K0b: wT[dout][din] = weight[din][dout]
  transpose_cvt_kernel<<<dim3(16, 16), 256, 0, stream>>>(weight, wT);
  // K1: fwT[dout][node] = wT @ fb16^T   M=512 (nmt=4), N=8192 (nnt=64, BN=128)
  gemm_bt32_kernel<0, 0, 2><<<256, 512, 0, stream>>>(wT, fb16, fwT,
                                                     4, 64, 16, 512, 512, 8192, 0);
  // K2: relu(adj @ fwT^T), 3-deep pipeline, k-split 4, grid 256
  if (have_part) {
    gemm_k2_pipe<3><<<256, 512, 0, stream>>>(adj, fwT, part, pstride);
    reduce4_relu_kernel<<<(N * D / 8) / 512, 512, 0, stream>>>(part, pstride, out);
  } else {
    hipMemsetAsync(d_out, 0, (size_t)N * D * sizeof(float), stream);
    gemm_k2_pipe<2><<<256, 512, 0, stream>>>(adj, fwT, out, 0);
    relu_inplace_kernel<<<(N * D / 4) / 512, 512, 0, stream>>>(out);
  }
}

// Round 7
// 140.538 us; speedup vs baseline: 1.2028x; 1.2028x over previous
//
#include <hip/hip_runtime.h>
#include <hip/hip_bf16.h>
#include <stdint.h>

typedef __bf16 bf16_t;
typedef __bf16 bf16x4 __attribute__((ext_vector_type(4)));
typedef __bf16 bf16x8 __attribute__((ext_vector_type(8)));
typedef float  f32x4  __attribute__((ext_vector_type(4)));

#define AS_GLOBAL __attribute__((address_space(1)))
#define AS_LDS    __attribute__((address_space(3)))

#define VMCNT(n)  asm volatile("s_waitcnt vmcnt(" #n ")" ::: "memory")
#define LGKMCNT0  asm volatile("s_waitcnt lgkmcnt(0)" ::: "memory")
#define SBARRIER  asm volatile("s_barrier" ::: "memory")
#define SCHEDB0   __builtin_amdgcn_sched_barrier(0)

__device__ __forceinline__ void gload_lds16(const void* g, void* l) {
  __builtin_amdgcn_global_load_lds((const AS_GLOBAL void*)g,
                                   (AS_LDS void*)l, 16, 0, 0);
}

// ---------------- K0a: f32 -> bf16 elementwise (8 elems/thread) ----------------
__global__ void cvt_f32_bf16_kernel(const float* __restrict__ in,
                                    bf16_t* __restrict__ out) {
  const int i = blockIdx.x * blockDim.x + threadIdx.x;
  f32x4 v0 = *(const f32x4*)&in[(size_t)i * 8];
  f32x4 v1 = *(const f32x4*)&in[(size_t)i * 8 + 4];
  bf16x8 o;
  o[0] = (bf16_t)v0[0]; o[1] = (bf16_t)v0[1]; o[2] = (bf16_t)v0[2]; o[3] = (bf16_t)v0[3];
  o[4] = (bf16_t)v1[0]; o[5] = (bf16_t)v1[1]; o[6] = (bf16_t)v1[2]; o[7] = (bf16_t)v1[3];
  *(bf16x8*)&out[(size_t)i * 8] = o;
}

// ---------------- K0b: weight [512][512] f32 -> wT bf16 (transpose) ----------------
__global__ void transpose_cvt_kernel(const float* __restrict__ in,
                                     bf16_t* __restrict__ out) {
  __shared__ float t[32][33];
  const int ti = blockIdx.x;
  const int tj = blockIdx.y;
  const int c = threadIdx.x & 31;
  const int r0 = threadIdx.x >> 5;
  #pragma unroll
  for (int p = 0; p < 4; ++p) {
    int r = r0 + p * 8;
    t[r][c] = in[(size_t)(ti * 32 + r) * 512 + tj * 32 + c];
  }
  __syncthreads();
  #pragma unroll
  for (int p = 0; p < 4; ++p) {
    int r = r0 + p * 8;
    out[(size_t)(tj * 32 + r) * 512 + ti * 32 + c] = (bf16_t)t[c][r];
  }
}

// ---------------- K1 GEMM-BT (bf16 A, stage-ahead dbuf) — unchanged ----------------
template<int NI>
__global__ __launch_bounds__(512, 2) void gemm_bt32_kernel(
    const bf16_t* __restrict__ Ab, const bf16_t* __restrict__ Bt,
    bf16_t* __restrict__ Cv, int nmt, int nnt, int ksteps,
    int lda, int ldb, int ldc) {
  constexpr int BM = 128, BK = 32, BN = NI * 64;
  __shared__ alignas(16) bf16_t Al[2][BM * BK];
  __shared__ alignas(16) bf16_t Bl[2][BN * BK];

  const int tid  = threadIdx.x;
  const int lane = tid & 63;
  const int w    = tid >> 6;
  const int wr   = w >> 2;
  const int wc   = w & 3;

  const int nwg = gridDim.x;
  const int cpx = nwg >> 3;
  const int bid = blockIdx.x;
  const int swz = (bid & 7) * cpx + (bid >> 3);
  const int nt  = swz / nmt;
  const int mt  = swz - nt * nmt;
  const int row0 = mt * BM;
  const int col0 = nt * BN;

  f32x4 acc[4][NI];
  #pragma unroll
  for (int mi = 0; mi < 4; ++mi)
    #pragma unroll
    for (int ni = 0; ni < NI; ++ni)
      acc[mi][ni] = (f32x4){0.f, 0.f, 0.f, 0.f};

  const int r4   = tid >> 2;
  const int g4   = tid & 3;
  const int gsrc = g4 ^ (r4 & 3);

  auto stageB = [&](int b, int k0) {
    #pragma unroll
    for (int i = 0; i < NI / 2; ++i)
      gload_lds16(&Bt[(size_t)(col0 + r4 + i * 128) * ldb + k0 + gsrc * 8],
                  &Bl[b][(tid + i * 512) * 8]);
  };
  auto stageA = [&](int b, int k0) {
    gload_lds16(&Ab[(size_t)(row0 + r4) * lda + k0 + gsrc * 8],
                &Al[b][tid * 8]);
  };

  stageB(0, 0);
  stageA(0, 0);
  __syncthreads();

  int cur = 0;
  for (int kt = 0; kt < ksteps; ++kt) {
    if (kt + 1 < ksteps) {
      stageB(cur ^ 1, (kt + 1) * BK);
      stageA(cur ^ 1, (kt + 1) * BK);
    }
    const int frow = lane & 15;
    const int gk = lane >> 4;
    bf16x8 a[4], b[NI];
    #pragma unroll
    for (int mi = 0; mi < 4; ++mi) {
      const int r = wr * 64 + mi * 16 + frow;
      a[mi] = *(const bf16x8*)&Al[cur][r * 32 + ((gk ^ (r & 3)) << 3)];
    }
    #pragma unroll
    for (int ni = 0; ni < NI; ++ni) {
      const int r = wc * (NI * 16) + ni * 16 + frow;
      b[ni] = *(const bf16x8*)&Bl[cur][r * 32 + ((gk ^ (r & 3)) << 3)];
    }
    #pragma unroll
    for (int mi = 0; mi < 4; ++mi)
      #pragma unroll
      for (int ni = 0; ni < NI; ++ni)
        acc[mi][ni] = __builtin_amdgcn_mfma_f32_16x16x32_bf16(a[mi], b[ni], acc[mi][ni], 0, 0, 0);
    __syncthreads();
    cur ^= 1;
  }

  const int rbase = row0 + wr * 64 + ((lane >> 4) << 2);
  const int cbase = col0 + wc * (NI * 16) + (lane & 15);
  #pragma unroll
  for (int mi = 0; mi < 4; ++mi)
    #pragma unroll
    for (int ni = 0; ni < NI; ++ni)
      #pragma unroll
      for (int j = 0; j < 4; ++j)
        Cv[(size_t)(rbase + mi * 16 + j) * ldc + cbase + ni * 16] =
            (bf16_t)acc[mi][ni][j];
}

// ---------------- K2 v3: adj(f32) @ fwT^T, phase-split counted-vmcnt pipeline ----
// BM=256, BN=256, BK=64, k-split 4 -> grid 256 (32mt x 2nt x 4ks), 512 thr,
// 8 waves 2M x 4N, wave out 128x64, acc[8][4]. LDS: A,B bf16 2x32KB each=128KB.
// A: f32 global -> 8 reg loads -> cvt -> 4 swizzled ds_write_b128 (T14 split).
// B: 4 global_load_lds, source-granule pre-swizzled. Rows 128B/8 granules,
// LDS slot = g ^ (row&7) both operands.
// Per K-tile t: [frag reads + MFMA mi0-3] vmcnt(4) [cvt+ds_write A(t+1)]
// [MFMA mi4-7] lgkm0 barrier [issue A(t+2) regs, B(t+2) gloads] vmcnt(12)
// barrier. vmcnt never 0 except last tiles (T4). setprio around MFMA (T5).
// XCD map: XCD = one ks (B-slice 2MB L2-resident); nt-pairs co-located (adj
// band HBM-fetched once, second reader L2-hits).
template<int EPI>  // 3: bf16 partial @ Cv+ks*pstride, 2: f32 atomicAdd
__global__ __launch_bounds__(512, 2) void gemm_k2_v3(
    const float* __restrict__ adj, const bf16_t* __restrict__ Bt,
    void* __restrict__ Cv, size_t pstride) {
  constexpr int NT = 32;
  __shared__ alignas(16) bf16_t Al[2][256 * 64];
  __shared__ alignas(16) bf16_t Bl[2][256 * 64];

  const int tid  = threadIdx.x;
  const int lane = tid & 63;
  const int w    = tid >> 6;
  const int wr   = w >> 2;   // 0..1
  const int wc   = w & 3;    // 0..3

  const int bid = blockIdx.x;
  const int swz = (bid & 7) * 32 + (bid >> 3);
  const int ks  = swz >> 6;         // 0..3 (2 XCDs per ks)
  const int rem = swz & 63;
  const int mt  = rem >> 1;         // 0..31
  const int nt  = rem & 1;
  const int row0 = mt * 256;
  const int col0 = nt * 256;
  const int kbase = ks * 2048;

  f32x4 acc[8][4];
  #pragma unroll
  for (int mi = 0; mi < 8; ++mi)
    #pragma unroll
    for (int ni = 0; ni < 4; ++ni)
      acc[mi][ni] = (f32x4){0.f, 0.f, 0.f, 0.f};

  const int sr = tid >> 3;          // staging base row (+64*i)
  const int sg = tid & 7;           // staging granule slot

  f32x4 areg[8];

  auto stageB = [&](int t, int b) {
    const size_t k0 = (size_t)kbase + t * 64;
    #pragma unroll
    for (int i = 0; i < 4; ++i) {
      const int r = sr + 64 * i;
      gload_lds16(&Bt[(size_t)(col0 + r) * 8192 + k0 + ((sg ^ (r & 7)) << 3)],
                  &Bl[b][(size_t)(tid + i * 512) * 8]);
    }
  };
  auto stageA_ld = [&](int t) {
    const size_t k0 = (size_t)kbase + t * 64;
    #pragma unroll
    for (int i = 0; i < 4; ++i) {
      const int r = sr + 64 * i;
      const float* p = &adj[(size_t)(row0 + r) * 8192 + k0 + sg * 8];
      areg[2 * i]     = *(const f32x4*)p;
      areg[2 * i + 1] = *(const f32x4*)(p + 4);
    }
  };
  auto stageA_wr = [&](int b) {
    #pragma unroll
    for (int i = 0; i < 4; ++i) {
      const int r = sr + 64 * i;
      bf16x8 v;
      v[0] = (bf16_t)areg[2 * i][0]; v[1] = (bf16_t)areg[2 * i][1];
      v[2] = (bf16_t)areg[2 * i][2]; v[3] = (bf16_t)areg[2 * i][3];
      v[4] = (bf16_t)areg[2 * i + 1][0]; v[5] = (bf16_t)areg[2 * i + 1][1];
      v[6] = (bf16_t)areg[2 * i + 1][2]; v[7] = (bf16_t)areg[2 * i + 1][3];
      *(bf16x8*)&Al[b][r * 64 + ((sg ^ (r & 7)) << 3)] = v;
    }
  };

  // ---- prologue ----
  stageA_ld(0); stageB(0, 0);       // queue: A0(8), B0(4)
  VMCNT(4); SCHEDB0;                // A0 landed, B0 flying
  stageA_wr(0);
  stageA_ld(1); stageB(1, 1);       // queue: B0(4), A1(8), B1(4)
  VMCNT(12); SCHEDB0;               // B0 landed
  LGKMCNT0; SCHEDB0;
  SBARRIER;                         // buf0 fully ready

  const int frow = lane & 15;
  const int gk   = lane >> 4;
  int cur = 0;
  for (int t = 0; t < NT; ++t) {
    // B fragments for both kk (kept in regs across both MFMA halves)
    bf16x8 bf[4][2];
    #pragma unroll
    for (int ni = 0; ni < 4; ++ni) {
      const int r = wc * 64 + ni * 16 + frow;
      #pragma unroll
      for (int kk = 0; kk < 2; ++kk)
        bf[ni][kk] = *(const bf16x8*)&Bl[cur][r * 64 + ((((kk << 2) | gk) ^ (r & 7)) << 3)];
    }
    // half 1: mi 0..3
    __builtin_amdgcn_s_setprio(1);
    #pragma unroll
    for (int mi = 0; mi < 4; ++mi) {
      const int r = wr * 128 + mi * 16 + frow;
      bf16x8 a0 = *(const bf16x8*)&Al[cur][r * 64 + ((gk ^ (r & 7)) << 3)];
      bf16x8 a1 = *(const bf16x8*)&Al[cur][r * 64 + (((4 | gk) ^ (r & 7)) << 3)];
      #pragma unroll
      for (int ni = 0; ni < 4; ++ni) {
        acc[mi][ni] = __builtin_amdgcn_mfma_f32_16x16x32_bf16(a0, bf[ni][0], acc[mi][ni], 0, 0, 0);
        acc[mi][ni] = __builtin_amdgcn_mfma_f32_16x16x32_bf16(a1, bf[ni][1], acc[mi][ni], 0, 0, 0);
      }
    }
    __builtin_amdgcn_s_setprio(0);
    // A(t+1) regs landed -> cvt + swizzled ds_write into the other buffer
    if (t + 1 < NT) {
      VMCNT(4); SCHEDB0;            // queue was A(t+1)(8), B(t+1)(4)
      stageA_wr(cur ^ 1);
    }
    // half 2: mi 4..7
    __builtin_amdgcn_s_setprio(1);
    #pragma unroll
    for (int mi = 4; mi < 8; ++mi) {
      const int r = wr * 128 + mi * 16 + frow;
      bf16x8 a0 = *(const bf16x8*)&Al[cur][r * 64 + ((gk ^ (r & 7)) << 3)];
      bf16x8 a1 = *(const bf16x8*)&Al[cur][r * 64 + (((4 | gk) ^ (r & 7)) << 3)];
      #pragma unroll
      for (int ni = 0; ni < 4; ++ni) {
        acc[mi][ni] = __builtin_amdgcn_mfma_f32_16x16x32_bf16(a0, bf[ni][0], acc[mi][ni], 0, 0, 0);
        acc[mi][ni] = __builtin_amdgcn_mfma_f32_16x16x32_bf16(a1, bf[ni][1], acc[mi][ni], 0, 0, 0);
      }
    }
    __builtin_amdgcn_s_setprio(0);
    LGKMCNT0; SCHEDB0;
    SBARRIER;                       // all waves done reading buf cur; A-writes visible
    if (t + 2 < NT) {
      stageA_ld(t + 2);             // regs (issued before B so vmcnt(4) isolates A)
      stageB(t + 2, cur);           // overwrite just-freed B region
      VMCNT(12); SCHEDB0;           // queue: B(t+1)(4), A(t+2)(8), B(t+2)(4) -> B(t+1) done
    } else if (t + 1 < NT) {
      VMCNT(0); SCHEDB0;            // tail: only B(t+1) outstanding
    }
    SBARRIER;                       // buf^1 fully ready for tile t+1
    cur ^= 1;
  }

  // epilogue: C/D layout col=lane&15, row=(lane>>4)*4+reg  [m89-verified]
  const int rbase = row0 + wr * 128 + ((lane >> 4) << 2);
  const int cbase = col0 + wc * 64 + (lane & 15);
  if constexpr (EPI == 3) {
    bf16_t* C = (bf16_t*)Cv + (size_t)ks * pstride;
    #pragma unroll
    for (int mi = 0; mi < 8; ++mi)
      #pragma unroll
      for (int ni = 0; ni < 4; ++ni)
        #pragma unroll
        for (int j = 0; j < 4; ++j)
          C[(size_t)(rbase + mi * 16 + j) * 512 + cbase + ni * 16] =
              (bf16_t)acc[mi][ni][j];
  } else {
    float* C = (float*)Cv;
    #pragma unroll
    for (int mi = 0; mi < 8; ++mi)
      #pragma unroll
      for (int ni = 0; ni < 4; ++ni)
        #pragma unroll
        for (int j = 0; j < 4; ++j)
          atomicAdd(&C[(size_t)(rbase + mi * 16 + j) * 512 + cbase + ni * 16],
                    acc[mi][ni][j]);
  }
}

// ---------------- reduce 4 bf16 partials + relu -> f32 ----------------
__global__ void reduce4_relu_kernel(const bf16_t* __restrict__ part,
                                    size_t pstride, float* __restrict__ out) {
  const size_t i8 = ((size_t)blockIdx.x * blockDim.x + threadIdx.x) * 8;
  float s[8];
  #pragma unroll
  for (int j = 0; j < 8; ++j) s[j] = 0.f;
  #pragma unroll
  for (int p = 0; p < 4; ++p) {
    bf16x8 v = *(const bf16x8*)&part[p * pstride + i8];
    #pragma unroll
    for (int j = 0; j < 8; ++j) s[j] += (float)v[j];
  }
  f32x4 r0, r1;
  r0[0] = fmaxf(s[0], 0.f); r0[1] = fmaxf(s[1], 0.f);
  r0[2] = fmaxf(s[2], 0.f); r0[3] = fmaxf(s[3], 0.f);
  r1[0] = fmaxf(s[4], 0.f); r1[1] = fmaxf(s[5], 0.f);
  r1[2] = fmaxf(s[6], 0.f); r1[3] = fmaxf(s[7], 0.f);
  *(f32x4*)&out[i8] = r0;
  *(f32x4*)&out[i8 + 4] = r1;
}

// ---------------- in-place relu (atomic fallback) ----------------
__global__ void relu_inplace_kernel(float* __restrict__ out) {
  const size_t i = ((size_t)blockIdx.x * blockDim.x + threadIdx.x) * 4;
  f32x4 a = *(const f32x4*)&out[i];
  f32x4 r;
  r[0] = fmaxf(a[0], 0.f); r[1] = fmaxf(a[1], 0.f);
  r[2] = fmaxf(a[2], 0.f); r[3] = fmaxf(a[3], 0.f);
  *(f32x4*)&out[i] = r;
}

extern "C" void kernel_launch(void* const* d_in, const int* in_sizes, int n_in,
                              void* d_out, int out_size, void* d_ws, size_t ws_size,
                              hipStream_t stream) {
  const int N = 8192, D = 512;
  const float* features = (const float*)d_in[0];  // [N][D]
  const float* adj      = (const float*)d_in[1];  // [N][N]
  const float* weight   = (const float*)d_in[2];  // [D][D]
  float* out = (float*)d_out;                     // [N][D] f32

  char* ws = (char*)d_ws;
  bf16_t* fb16 = (bf16_t*)ws;                                    // 8.39 MB
  bf16_t* wT   = (bf16_t*)(ws + (size_t)N * D * 2);              // 0.52 MB
  bf16_t* fwT  = (bf16_t*)(ws + (size_t)N * D * 2 + (size_t)D * D * 2);  // 8.39 MB
  const size_t base_bytes = (size_t)N * D * 2 * 2 + (size_t)D * D * 2;   // 17.3 MB
  bf16_t* part = (bf16_t*)(ws + base_bytes);      // 4 x 8.39 MB bf16 partials
  const size_t pstride = (size_t)N * D;
  const bool have_part = ws_size >= base_bytes + 4 * pstride * sizeof(bf16_t);

  // K0a: features f32 -> bf16
  cvt_f32_bf16_kernel<<<(N * D / 8) / 256, 256, 0, stream>>>(features, fb16);
  // K0b: wT[dout][din] = weight[din][dout]
  transpose_cvt_kernel<<<dim3(16, 16), 256, 0, stream>>>(weight, wT);
  // K1: fwT[dout][node] = wT @ fb16^T   M=512 (nmt=4), N=8192 (nnt=64, BN=128)
  gemm_bt32_kernel<2><<<256, 512, 0, stream>>>(wT, fb16, fwT,
                                               4, 64, 16, 512, 512, 8192);
  // K2: relu(adj @ fwT^T), phase-split counted-vmcnt pipeline, grid 256
  if (have_part) {
    gemm_k2_v3<3><<<256, 512, 0, stream>>>(adj, fwT, part, pstride);
    reduce4_relu_kernel<<<(N * D / 8) / 512, 512, 0, stream>>>(part, pstride, out);
  } else {
    hipMemsetAsync(d_out, 0, (size_t)N * D * sizeof(float), stream);
    gemm_k2_v3<2><<<256, 512, 0, stream>>>(adj, fwT, out, 0);
    relu_inplace_kernel<<<(N * D / 4) / 512, 512, 0, stream>>>(out);
  }
}